// Round 10
// baseline (173.136 us; speedup 1.0000x reference)
//
#include <hip/hip_runtime.h>
#include <math.h>

#define RES 128
#define NS 64
#define EPSF 1e-8f
#define ZSL 8             // slab thickness (z voxels)
#define NSLAB (RES / ZSL) // 16
#define WXS 20            // staged lateral window x extent
#define WYS 20            // staged lateral window y extent
#define WROW 21           // padded row stride (21 co-prime w/ 32 banks)
#define ZPL 9             // staged z planes (ZSL + 1 shared face)

// Round 3/6/9 evidence: 86.7us baseline; 2x waves -> null; halved gather
// instrs -> null; VALUBusy pinned ~26%. Surviving model: L1 gathered-dword
// return/miss-queue bound (~2.5 dw/cyc/CU). Fix: do the 8-corner interp
// from LDS (z-slab staged frustum window), global path kept as fallback.

// General 4x4 inverse, Gauss-Jordan with partial pivoting, double internal.
__device__ void inv4x4(const float* __restrict__ A, double out[4][4]) {
    double m[4][8];
    for (int r = 0; r < 4; ++r) {
        for (int c = 0; c < 4; ++c) {
            m[r][c]     = (double)A[r * 4 + c];
            m[r][c + 4] = (r == c) ? 1.0 : 0.0;
        }
    }
    for (int col = 0; col < 4; ++col) {
        int piv = col;
        double best = fabs(m[col][col]);
        for (int r = col + 1; r < 4; ++r) {
            double v = fabs(m[r][col]);
            if (v > best) { best = v; piv = r; }
        }
        if (piv != col) {
            for (int c = 0; c < 8; ++c) {
                double t = m[col][c]; m[col][c] = m[piv][c]; m[piv][c] = t;
            }
        }
        double inv = 1.0 / m[col][col];
        for (int c = 0; c < 8; ++c) m[col][c] *= inv;
        for (int r = 0; r < 4; ++r) {
            if (r == col) continue;
            double f = m[r][col];
            for (int c = 0; c < 8; ++c) m[r][c] -= f * m[col][c];
        }
    }
    for (int r = 0; r < 4; ++r)
        for (int c = 0; c < 4; ++c)
            out[r][c] = m[r][c + 4];
}

// 8-byte pair load from a 4-byte-aligned address, without UB.
__device__ __forceinline__ float2 load_f2(const float* __restrict__ p) {
    float2 r;
    __builtin_memcpy(&r, p, 8);
    return r;
}

// Zero-padding corner fetch; NaN-safe (NaN coords fail the tests -> 0).
__device__ __forceinline__ float cornerf(const float* __restrict__ vol,
                                         float xf, float yf, float zf, float w) {
    if (xf >= 0.f && xf <= 127.f &&
        yf >= 0.f && yf <= 127.f &&
        zf >= 0.f && zf <= 127.f) {
        int xi = (int)xf, yi = (int)yf, zi = (int)zf;
        return vol[(zi * RES + yi) * RES + xi] * w;
    }
    return 0.f;
}

__global__ __launch_bounds__(256) void dsv_render(
    const float* __restrict__ vol,
    const float* __restrict__ wvt,
    const float* __restrict__ proj,
    const float* __restrict__ cam,
    const float* __restrict__ bbox,
    const int*   __restrict__ pH,
    const int*   __restrict__ pW,
    const int*   __restrict__ pmode,
    float*       __restrict__ out)
{
    __shared__ float sC[28];
    __shared__ float crp[4][6];            // 4 tile-corner rays: base.xyz, q.xyz
    __shared__ int   win[NSLAB][2];        // per-slab window origin (wx0, wy0)
    __shared__ float slab[ZPL][WYS][WROW]; // staged volume window

    const int H = pH[0];
    const int W = pW[0];
    const int mode = pmode[0];

    if (threadIdx.x == 0) {
        double vi[4][4], pinv[4][4];
        inv4x4(wvt, vi);
        inv4x4(proj, pinv);
        for (int i = 0; i < 4; ++i) {
            for (int j = 0; j < 4; ++j) {
                double s = 0.0;
                for (int k = 0; k < 4; ++k) s += pinv[i][k] * vi[k][j];
                sC[i * 4 + j] = (float)s;
            }
        }
        float bminx = bbox[0], bminy = bbox[1], bminz = bbox[2];
        float bmaxx = bbox[3], bmaxy = bbox[4], bmaxz = bbox[5];
        float ex = bmaxx - bminx, ey = bmaxy - bminy, ez = bmaxz - bminz;
        float ddx = -(float)vi[2][0], ddy = -(float)vi[2][1], ddz = -(float)vi[2][2];
        float nn = sqrtf(ddx * ddx + ddy * ddy + ddz * ddz) + EPSF;
        ddx /= nn; ddy /= nn; ddz /= nn;
        float diag = sqrtf(ex * ex + ey * ey + ez * ez);
        sC[16] = ddx; sC[17] = ddy; sC[18] = ddz;
        sC[19] = (float)vi[0][0] * ex * 0.5f;
        sC[20] = (float)vi[0][1] * ex * 0.5f;
        sC[21] = (float)vi[0][2] * ex * 0.5f;
        sC[22] = (float)vi[1][0] * ey * 0.5f;
        sC[23] = (float)vi[1][1] * ey * 0.5f;
        sC[24] = (float)vi[1][2] * ey * 0.5f;
        sC[25] = (bminx + bmaxx) * 0.5f - ddx * diag * 0.5f;
        sC[26] = (bminy + bmaxy) * 0.5f - ddy * diag * 0.5f;
        sC[27] = (bminz + bmaxz) * 0.5f - ddz * diag * 0.5f;
    }
    __syncthreads();

    const float bminx = bbox[0], bminy = bbox[1], bminz = bbox[2];
    const float bmaxx = bbox[3], bmaxy = bbox[4], bmaxz = bbox[5];
    const float kx = 127.0f / (bmaxx - bminx + EPSF);
    const float ky = 127.0f / (bmaxy - bminy + EPSF);
    const float kz = 127.0f / (bmaxz - bminz + EPSF);
    const float camx = cam[0], camy = cam[1], camz = cam[2];

    const int nTx = (W + 15) >> 4;
    const int nTy = (H + 15) >> 4;
    const int nTiles = nTx * nTy;
    const int tid = (int)threadIdx.x;

    for (int tile = blockIdx.x; tile < nTiles; tile += gridDim.x) {
        const int ti = tile / nTx;
        const int tj = tile - ti * nTx;
        const int i = ti * 16 + (tid >> 4);
        const int j = tj * 16 + (tid & 15);
        const bool inImg = (i < H) && (j < W);

        const float nx = (float)j / (float)(W - 1) * 2.0f - 1.0f;
        const float ny = (float)i / (float)(H - 1) * 2.0f - 1.0f;

        float ox, oy, oz, dx, dy, dz;
        if (mode == 0) {
            dx = sC[16]; dy = sC[17]; dz = sC[18];
            ox = sC[25] + nx * sC[19] + ny * sC[22];
            oy = sC[26] + nx * sC[20] + ny * sC[23];
            oz = sC[27] + nx * sC[21] + ny * sC[24];
        } else {
            float wx = nx * sC[0] + ny * sC[4] + sC[8]  + sC[12];
            float wy = nx * sC[1] + ny * sC[5] + sC[9]  + sC[13];
            float wz = nx * sC[2] + ny * sC[6] + sC[10] + sC[14];
            float ww = nx * sC[3] + ny * sC[7] + sC[11] + sC[15];
            float invw = 1.0f / (ww + EPSF);
            wx *= invw; wy *= invw; wz *= invw;
            ox = camx; oy = camy; oz = camz;
            dx = wx - ox; dy = wy - oy; dz = wz - oz;
            float n = sqrtf(dx * dx + dy * dy + dz * dz) + EPSF;
            dx /= n; dy /= n; dz /= n;
        }

        // AABB slab test (with reference's +EPS on dir)
        const float ix = 1.0f / (dx + EPSF);
        const float iy = 1.0f / (dy + EPSF);
        const float iz = 1.0f / (dz + EPSF);
        float t1 = (bminx - ox) * ix, t2 = (bmaxx - ox) * ix;
        float tn = fminf(t1, t2), tf = fmaxf(t1, t2);
        t1 = (bminy - oy) * iy; t2 = (bmaxy - oy) * iy;
        tn = fmaxf(tn, fminf(t1, t2)); tf = fminf(tf, fmaxf(t1, t2));
        t1 = (bminz - oz) * iz; t2 = (bmaxz - oz) * iz;
        tn = fmaxf(tn, fminf(t1, t2)); tf = fminf(tf, fmaxf(t1, t2));
        tn = fmaxf(tn, 0.0f);
        const bool valid = tf > tn;
        const float range = tf - tn;

        // Per-ray affine into voxel space: c(s) = base + q * s, s = 0..63
        const float sdx = dx * kx, sdy = dy * ky, sdz = dz * kz;
        const float basex = fmaf(sdx, tn, (ox - bminx) * kx);
        const float basey = fmaf(sdy, tn, (oy - bminy) * ky);
        const float basez = fmaf(sdz, tn, (oz - bminz) * kz);
        const float r63 = range * (1.0f / 63.0f);
        const float qx = sdx * r63, qy = sdy * r63, qz = sdz * r63;

        // Publish tile-corner rays (pixels (0,0),(0,15),(15,0),(15,15))
        int cidx = -1;
        if      (tid == 0)   cidx = 0;
        else if (tid == 15)  cidx = 1;
        else if (tid == 240) cidx = 2;
        else if (tid == 255) cidx = 3;
        if (cidx >= 0) {
            crp[cidx][0] = basex; crp[cidx][1] = basey; crp[cidx][2] = basez;
            crp[cidx][3] = qx;    crp[cidx][4] = qy;    crp[cidx][5] = qz;
        }
        __syncthreads();

        const bool ok = (mode != 0)
            && fabsf(crp[0][5]) > 1e-4f && fabsf(crp[1][5]) > 1e-4f
            && fabsf(crp[2][5]) > 1e-4f && fabsf(crp[3][5]) > 1e-4f;

        float sum = 0.0f;

        if (ok) {
            // Per-slab lateral window from the 4 corner ray LINES evaluated
            // at the slab's z-planes (bounds all tile rays at fixed z).
            if (tid < NSLAB) {
                const float z0p = (float)(tid * ZSL);
                const float z1p = (float)(tid * ZSL + ZSL);
                float mnx = 1e30f, mxx = -1e30f, mny = 1e30f, mxy = -1e30f;
                #pragma unroll
                for (int c = 0; c < 4; ++c) {
                    const float bx = crp[c][0], by = crp[c][1], bz = crp[c][2];
                    const float cqx = crp[c][3], cqy = crp[c][4], cqz = crp[c][5];
                    const float iq = 1.0f / cqz;
                    const float s0 = (z0p - bz) * iq;
                    const float s1 = (z1p - bz) * iq;
                    const float xa = fmaf(cqx, s0, bx), xb = fmaf(cqx, s1, bx);
                    const float ya = fmaf(cqy, s0, by), yb = fmaf(cqy, s1, by);
                    mnx = fminf(mnx, fminf(xa, xb)); mxx = fmaxf(mxx, fmaxf(xa, xb));
                    mny = fminf(mny, fminf(ya, yb)); mxy = fmaxf(mxy, fmaxf(ya, yb));
                }
                mnx = fminf(fmaxf(mnx, -1e6f), 1e6f);
                mny = fminf(fmaxf(mny, -1e6f), 1e6f);
                win[tid][0] = (int)floorf(mnx) - 1;
                win[tid][1] = (int)floorf(mny) - 1;
            }

            int sc = 0;
            for (int k = 0; k < NSLAB; ++k) {
                __syncthreads();   // win ready (k=0) / prev slab consumed
                const int wx0 = win[k][0];
                const int wy0 = win[k][1];
                const int zk  = k * ZSL;

                // Stage window (zero-fill outside volume = reference padding)
                for (int t = tid; t < ZPL * WYS * WXS; t += 256) {
                    const int z = t / (WYS * WXS);
                    const int r = t - z * (WYS * WXS);
                    const int y = r / WXS;
                    const int x = r - y * WXS;
                    const int gz = zk + z, gy = wy0 + y, gx = wx0 + x;
                    float v = 0.0f;
                    if (gz < RES && (unsigned)gy < RES && (unsigned)gx < RES)
                        v = vol[(gz * RES + gy) * RES + gx];
                    slab[z][y][x] = v;
                }
                __syncthreads();

                const float zend = (k == NSLAB - 1) ? 1e30f : (float)(zk + ZSL);
                const float wx0f = (float)wx0, wy0f = (float)wy0;
                const float zkf = (float)zk;
                const float zhi = fminf(zkf + (float)(ZSL - 1), 126.0f);

                while (sc < NS) {
                    const float fs = (float)sc;
                    const float cz = fmaf(qz, fs, basez);
                    if (!(cz < zend)) break;   // NaN -> break; leftovers are 0-contrib
                    const float cx = fmaf(qx, fs, basex);
                    const float cy = fmaf(qy, fs, basey);
                    const float x0f = floorf(cx), y0f = floorf(cy), z0f = floorf(cz);
                    const float fx = cx - x0f, fy = cy - y0f, fz = cz - z0f;

                    if (x0f >= wx0f && x0f <= wx0f + 18.0f &&
                        y0f >= wy0f && y0f <= wy0f + 18.0f &&
                        z0f >= zkf  && z0f <= zhi) {
                        const int lx = (int)x0f - wx0;
                        const int ly = (int)y0f - wy0;
                        const int lz = (int)z0f - zk;
                        const float* p = &slab[lz][ly][lx];
                        const float a00 = p[0],            a01 = p[1];
                        const float a10 = p[WROW],         a11 = p[WROW + 1];
                        const float b00 = p[WYS * WROW],   b01 = p[WYS * WROW + 1];
                        const float b10 = p[WYS * WROW + WROW];
                        const float b11 = p[WYS * WROW + WROW + 1];
                        const float x00 = fmaf(fx, a01 - a00, a00);
                        const float x10 = fmaf(fx, a11 - a10, a10);
                        const float x01 = fmaf(fx, b01 - b00, b00);
                        const float x11 = fmaf(fx, b11 - b10, b10);
                        const float y0v = fmaf(fy, x10 - x00, x00);
                        const float y1v = fmaf(fy, x11 - x01, x01);
                        sum += fmaf(fz, y1v - y0v, y0v);
                    } else {
                        const float gxw = 1.0f - fx, gyw = 1.0f - fy, gzw = 1.0f - fz;
                        sum += cornerf(vol, x0f,       y0f,       z0f,       gxw * gyw * gzw);
                        sum += cornerf(vol, x0f + 1.f, y0f,       z0f,       fx  * gyw * gzw);
                        sum += cornerf(vol, x0f,       y0f + 1.f, z0f,       gxw * fy  * gzw);
                        sum += cornerf(vol, x0f + 1.f, y0f + 1.f, z0f,       fx  * fy  * gzw);
                        sum += cornerf(vol, x0f,       y0f,       z0f + 1.f, gxw * gyw * fz);
                        sum += cornerf(vol, x0f + 1.f, y0f,       z0f + 1.f, fx  * gyw * fz);
                        sum += cornerf(vol, x0f,       y0f + 1.f, z0f + 1.f, gxw * fy  * fz);
                        sum += cornerf(vol, x0f + 1.f, y0f + 1.f, z0f + 1.f, fx  * fy  * fz);
                    }
                    ++sc;
                }
            }
        } else {
            // Direct-gather path (mode 0 / degenerate corner rays)
            #pragma unroll 4
            for (int s = 0; s < NS; ++s) {
                const float fs = (float)s;
                const float cx = fmaf(qx, fs, basex);
                const float cy = fmaf(qy, fs, basey);
                const float cz = fmaf(qz, fs, basez);
                const float x0 = floorf(cx), y0 = floorf(cy), z0 = floorf(cz);
                const float fx = cx - x0, fy = cy - y0, fz = cz - z0;
                const float gx = 1.0f - fx, gy = 1.0f - fy, gz = 1.0f - fz;

                if (x0 >= 0.f && x0 <= 126.f &&
                    y0 >= 0.f && y0 <= 126.f &&
                    z0 >= 0.f && z0 <= 126.f) {
                    const int base = (((int)z0) * RES + ((int)y0)) * RES + ((int)x0);
                    const float2 vA = load_f2(vol + base);
                    const float2 vB = load_f2(vol + base + RES);
                    const float2 vC = load_f2(vol + base + RES * RES);
                    const float2 vD = load_f2(vol + base + RES * RES + RES);
                    const float gygz = gy * gz, fygz = fy * gz;
                    const float gyfz = gy * fz, fyfz = fy * fz;
                    sum += (vA.x * gx + vA.y * fx) * gygz
                         + (vB.x * gx + vB.y * fx) * fygz
                         + (vC.x * gx + vC.y * fx) * gyfz
                         + (vD.x * gx + vD.y * fx) * fyfz;
                } else {
                    sum += cornerf(vol, x0,       y0,       z0,       gx * gy * gz);
                    sum += cornerf(vol, x0 + 1.f, y0,       z0,       fx * gy * gz);
                    sum += cornerf(vol, x0,       y0 + 1.f, z0,       gx * fy * gz);
                    sum += cornerf(vol, x0 + 1.f, y0 + 1.f, z0,       fx * fy * gz);
                    sum += cornerf(vol, x0,       y0,       z0 + 1.f, gx * gy * fz);
                    sum += cornerf(vol, x0 + 1.f, y0,       z0 + 1.f, fx * gy * fz);
                    sum += cornerf(vol, x0,       y0 + 1.f, z0 + 1.f, gx * fy * fz);
                    sum += cornerf(vol, x0 + 1.f, y0 + 1.f, z0 + 1.f, fx * fy * fz);
                }
            }
        }

        if (inImg) {
            const float delta = range * (1.0f / 64.0f);
            out[i * W + j] = valid ? sum * delta : 0.0f;
        }
    }
}

extern "C" void kernel_launch(void* const* d_in, const int* in_sizes, int n_in,
                              void* d_out, int out_size, void* d_ws, size_t ws_size,
                              hipStream_t stream) {
    const float* vol  = (const float*)d_in[0];
    const float* wvt  = (const float*)d_in[1];
    const float* proj = (const float*)d_in[2];
    const float* cam  = (const float*)d_in[3];
    const float* bbox = (const float*)d_in[4];
    const int*   pH   = (const int*)d_in[5];
    const int*   pW   = (const int*)d_in[6];
    const int*   pmode= (const int*)d_in[7];
    float* out = (float*)d_out;

    int blocks = (out_size + 255) / 256;
    if (blocks < 1) blocks = 1;
    dsv_render<<<blocks, 256, 0, stream>>>(vol, wvt, proj, cam, bbox, pH, pW, pmode, out);
}

// Round 11
// 131.364 us; speedup vs baseline: 1.3180x; 1.3180x over previous
//
#include <hip/hip_runtime.h>
#include <math.h>

#define RES 128
#define NS 64
#define EPSF 1e-8f
#define ZSL 8             // slab thickness (z voxels)
#define NSLAB (RES / ZSL) // 16
#define WXS 16            // staged lateral window x extent
#define WYS 16            // staged lateral window y extent
#define WROW 17           // padded row stride
#define ZPL 9             // staged z planes (ZSL + 1 shared face)

// Model (r3/r6/r9 confirmed): direct gather path is L1 unique-line-service
// bound (~1 line/cyc/CU) -> 88us floor regardless of waves/instr count.
// r10: LDS slab interp works but staging div/mod VALU cost +10K instr/thread.
// This round: div/mod-free staging (fixed per-thread column, 9 z-planes),
// cheap unsigned window tests. Global cornerf fallback keeps correctness
// independent of the window heuristic.

// General 4x4 inverse, Gauss-Jordan with partial pivoting, double internal.
__device__ void inv4x4(const float* __restrict__ A, double out[4][4]) {
    double m[4][8];
    for (int r = 0; r < 4; ++r) {
        for (int c = 0; c < 4; ++c) {
            m[r][c]     = (double)A[r * 4 + c];
            m[r][c + 4] = (r == c) ? 1.0 : 0.0;
        }
    }
    for (int col = 0; col < 4; ++col) {
        int piv = col;
        double best = fabs(m[col][col]);
        for (int r = col + 1; r < 4; ++r) {
            double v = fabs(m[r][col]);
            if (v > best) { best = v; piv = r; }
        }
        if (piv != col) {
            for (int c = 0; c < 8; ++c) {
                double t = m[col][c]; m[col][c] = m[piv][c]; m[piv][c] = t;
            }
        }
        double inv = 1.0 / m[col][col];
        for (int c = 0; c < 8; ++c) m[col][c] *= inv;
        for (int r = 0; r < 4; ++r) {
            if (r == col) continue;
            double f = m[r][col];
            for (int c = 0; c < 8; ++c) m[r][c] -= f * m[col][c];
        }
    }
    for (int r = 0; r < 4; ++r)
        for (int c = 0; c < 4; ++c)
            out[r][c] = m[r][c + 4];
}

// 8-byte pair load from a 4-byte-aligned address, without UB.
__device__ __forceinline__ float2 load_f2(const float* __restrict__ p) {
    float2 r;
    __builtin_memcpy(&r, p, 8);
    return r;
}

// Zero-padding corner fetch; NaN-safe (NaN coords fail the tests -> 0).
__device__ __forceinline__ float cornerf(const float* __restrict__ vol,
                                         float xf, float yf, float zf, float w) {
    if (xf >= 0.f && xf <= 127.f &&
        yf >= 0.f && yf <= 127.f &&
        zf >= 0.f && zf <= 127.f) {
        int xi = (int)xf, yi = (int)yf, zi = (int)zf;
        return vol[(zi * RES + yi) * RES + xi] * w;
    }
    return 0.f;
}

__global__ __launch_bounds__(256) void dsv_render(
    const float* __restrict__ vol,
    const float* __restrict__ wvt,
    const float* __restrict__ proj,
    const float* __restrict__ cam,
    const float* __restrict__ bbox,
    const int*   __restrict__ pH,
    const int*   __restrict__ pW,
    const int*   __restrict__ pmode,
    float*       __restrict__ out)
{
    __shared__ float sC[28];
    __shared__ float crp[4][6];            // 4 tile-corner rays: base.xyz, q.xyz
    __shared__ int   win[NSLAB][2];        // per-slab window origin (wx0, wy0)
    __shared__ float slab[ZPL][WYS][WROW]; // staged volume window (~9.6 KB)

    const int H = pH[0];
    const int W = pW[0];
    const int mode = pmode[0];

    if (threadIdx.x == 0) {
        double vi[4][4], pinv[4][4];
        inv4x4(wvt, vi);
        inv4x4(proj, pinv);
        for (int i = 0; i < 4; ++i) {
            for (int j = 0; j < 4; ++j) {
                double s = 0.0;
                for (int k = 0; k < 4; ++k) s += pinv[i][k] * vi[k][j];
                sC[i * 4 + j] = (float)s;
            }
        }
        float bminx = bbox[0], bminy = bbox[1], bminz = bbox[2];
        float bmaxx = bbox[3], bmaxy = bbox[4], bmaxz = bbox[5];
        float ex = bmaxx - bminx, ey = bmaxy - bminy, ez = bmaxz - bminz;
        float ddx = -(float)vi[2][0], ddy = -(float)vi[2][1], ddz = -(float)vi[2][2];
        float nn = sqrtf(ddx * ddx + ddy * ddy + ddz * ddz) + EPSF;
        ddx /= nn; ddy /= nn; ddz /= nn;
        float diag = sqrtf(ex * ex + ey * ey + ez * ez);
        sC[16] = ddx; sC[17] = ddy; sC[18] = ddz;
        sC[19] = (float)vi[0][0] * ex * 0.5f;
        sC[20] = (float)vi[0][1] * ex * 0.5f;
        sC[21] = (float)vi[0][2] * ex * 0.5f;
        sC[22] = (float)vi[1][0] * ey * 0.5f;
        sC[23] = (float)vi[1][1] * ey * 0.5f;
        sC[24] = (float)vi[1][2] * ey * 0.5f;
        sC[25] = (bminx + bmaxx) * 0.5f - ddx * diag * 0.5f;
        sC[26] = (bminy + bmaxy) * 0.5f - ddy * diag * 0.5f;
        sC[27] = (bminz + bmaxz) * 0.5f - ddz * diag * 0.5f;
    }
    __syncthreads();

    const float bminx = bbox[0], bminy = bbox[1], bminz = bbox[2];
    const float bmaxx = bbox[3], bmaxy = bbox[4], bmaxz = bbox[5];
    const float kx = 127.0f / (bmaxx - bminx + EPSF);
    const float ky = 127.0f / (bmaxy - bminy + EPSF);
    const float kz = 127.0f / (bmaxz - bminz + EPSF);
    const float camx = cam[0], camy = cam[1], camz = cam[2];

    const int nTx = (W + 15) >> 4;
    const int nTy = (H + 15) >> 4;
    const int nTiles = nTx * nTy;
    const int tid = (int)threadIdx.x;
    const int tx = tid & 15;
    const int ty = tid >> 4;

    for (int tile = blockIdx.x; tile < nTiles; tile += gridDim.x) {
        const int ti = tile / nTx;
        const int tj = tile - ti * nTx;
        const int i = ti * 16 + ty;
        const int j = tj * 16 + tx;
        const bool inImg = (i < H) && (j < W);

        const float nx = (float)j / (float)(W - 1) * 2.0f - 1.0f;
        const float ny = (float)i / (float)(H - 1) * 2.0f - 1.0f;

        float ox, oy, oz, dx, dy, dz;
        if (mode == 0) {
            dx = sC[16]; dy = sC[17]; dz = sC[18];
            ox = sC[25] + nx * sC[19] + ny * sC[22];
            oy = sC[26] + nx * sC[20] + ny * sC[23];
            oz = sC[27] + nx * sC[21] + ny * sC[24];
        } else {
            float wx = nx * sC[0] + ny * sC[4] + sC[8]  + sC[12];
            float wy = nx * sC[1] + ny * sC[5] + sC[9]  + sC[13];
            float wz = nx * sC[2] + ny * sC[6] + sC[10] + sC[14];
            float ww = nx * sC[3] + ny * sC[7] + sC[11] + sC[15];
            float invw = 1.0f / (ww + EPSF);
            wx *= invw; wy *= invw; wz *= invw;
            ox = camx; oy = camy; oz = camz;
            dx = wx - ox; dy = wy - oy; dz = wz - oz;
            float n = sqrtf(dx * dx + dy * dy + dz * dz) + EPSF;
            dx /= n; dy /= n; dz /= n;
        }

        // AABB slab test (with reference's +EPS on dir)
        const float ix = 1.0f / (dx + EPSF);
        const float iy = 1.0f / (dy + EPSF);
        const float iz = 1.0f / (dz + EPSF);
        float t1 = (bminx - ox) * ix, t2 = (bmaxx - ox) * ix;
        float tn = fminf(t1, t2), tf = fmaxf(t1, t2);
        t1 = (bminy - oy) * iy; t2 = (bmaxy - oy) * iy;
        tn = fmaxf(tn, fminf(t1, t2)); tf = fminf(tf, fmaxf(t1, t2));
        t1 = (bminz - oz) * iz; t2 = (bmaxz - oz) * iz;
        tn = fmaxf(tn, fminf(t1, t2)); tf = fminf(tf, fmaxf(t1, t2));
        tn = fmaxf(tn, 0.0f);
        const bool valid = tf > tn;
        const float range = tf - tn;

        // Per-ray affine into voxel space: c(s) = base + q * s, s = 0..63
        const float sdx = dx * kx, sdy = dy * ky, sdz = dz * kz;
        const float basex = fmaf(sdx, tn, (ox - bminx) * kx);
        const float basey = fmaf(sdy, tn, (oy - bminy) * ky);
        const float basez = fmaf(sdz, tn, (oz - bminz) * kz);
        const float r63 = range * (1.0f / 63.0f);
        const float qx = sdx * r63, qy = sdy * r63, qz = sdz * r63;

        // Publish tile-corner rays (pixels (0,0),(0,15),(15,0),(15,15))
        int cidx = -1;
        if      (tid == 0)   cidx = 0;
        else if (tid == 15)  cidx = 1;
        else if (tid == 240) cidx = 2;
        else if (tid == 255) cidx = 3;
        if (cidx >= 0) {
            crp[cidx][0] = basex; crp[cidx][1] = basey; crp[cidx][2] = basez;
            crp[cidx][3] = qx;    crp[cidx][4] = qy;    crp[cidx][5] = qz;
        }
        __syncthreads();

        const bool ok = (mode != 0)
            && fabsf(crp[0][5]) > 1e-4f && fabsf(crp[1][5]) > 1e-4f
            && fabsf(crp[2][5]) > 1e-4f && fabsf(crp[3][5]) > 1e-4f;

        float sum = 0.0f;

        if (ok) {
            // Per-slab lateral window from the 4 corner ray LINES at the
            // slab's bounding z-planes (bounds all tile rays at fixed z).
            if (tid < NSLAB) {
                const float z0p = (float)(tid * ZSL);
                const float z1p = (float)(tid * ZSL + ZSL);
                float mnx = 1e30f, mny = 1e30f;
                #pragma unroll
                for (int c = 0; c < 4; ++c) {
                    const float bx = crp[c][0], by = crp[c][1], bz = crp[c][2];
                    const float cqx = crp[c][3], cqy = crp[c][4], cqz = crp[c][5];
                    const float iq = 1.0f / cqz;
                    const float s0 = (z0p - bz) * iq;
                    const float s1 = (z1p - bz) * iq;
                    const float xa = fmaf(cqx, s0, bx), xb = fmaf(cqx, s1, bx);
                    const float ya = fmaf(cqy, s0, by), yb = fmaf(cqy, s1, by);
                    mnx = fminf(mnx, fminf(xa, xb));
                    mny = fminf(mny, fminf(ya, yb));
                }
                mnx = fminf(fmaxf(mnx, -1e6f), 1e6f);
                mny = fminf(fmaxf(mny, -1e6f), 1e6f);
                win[tid][0] = (int)floorf(mnx) - 1;
                win[tid][1] = (int)floorf(mny) - 1;
            }

            int sc = 0;
            for (int k = 0; k < NSLAB; ++k) {
                __syncthreads();   // win ready (k=0) / prev slab consumed
                const int wx0 = win[k][0];
                const int wy0 = win[k][1];
                const int zk  = k * ZSL;

                // Stage: each thread owns column (tx,ty), walks ZPL z-planes.
                // No div/mod; coalesced 16-float rows; zero-fill = padding.
                {
                    const int gx = wx0 + tx, gy = wy0 + ty;
                    const bool lat = ((unsigned)gx < RES) && ((unsigned)gy < RES);
                    unsigned gaddr = (unsigned)((zk * RES + gy) * RES + gx);
                    #pragma unroll
                    for (int z = 0; z < ZPL; ++z) {
                        float v = 0.0f;
                        if (lat && (zk + z) < RES) v = vol[gaddr];
                        slab[z][ty][tx] = v;
                        gaddr += RES * RES;
                    }
                }
                __syncthreads();

                const float zend = (k == NSLAB - 1) ? 1e30f : (float)(zk + ZSL);

                while (sc < NS) {
                    const float fs = (float)sc;
                    const float cz = fmaf(qz, fs, basez);
                    if (!(cz < zend)) break;   // NaN -> break (0 contribution)
                    const float cx = fmaf(qx, fs, basex);
                    const float cy = fmaf(qy, fs, basey);
                    const float x0f = floorf(cx), y0f = floorf(cy), z0f = floorf(cz);
                    const float fx = cx - x0f, fy = cy - y0f, fz = cz - z0f;
                    const int ix0 = (int)x0f, iy0 = (int)y0f, iz0 = (int)z0f;

                    if ((unsigned)(ix0 - wx0) <= (unsigned)(WXS - 2) &&
                        (unsigned)(iy0 - wy0) <= (unsigned)(WYS - 2) &&
                        (unsigned)(iz0 - zk)  <= (unsigned)(ZSL - 1) &&
                        x0f == x0f) {
                        const int lx = ix0 - wx0;
                        const int ly = iy0 - wy0;
                        const int lz = iz0 - zk;
                        const float* p = &slab[lz][ly][lx];
                        const float a00 = p[0],          a01 = p[1];
                        const float a10 = p[WROW],       a11 = p[WROW + 1];
                        const float b00 = p[WYS * WROW], b01 = p[WYS * WROW + 1];
                        const float b10 = p[WYS * WROW + WROW];
                        const float b11 = p[WYS * WROW + WROW + 1];
                        const float x00 = fmaf(fx, a01 - a00, a00);
                        const float x10 = fmaf(fx, a11 - a10, a10);
                        const float x01 = fmaf(fx, b01 - b00, b00);
                        const float x11 = fmaf(fx, b11 - b10, b10);
                        const float y0v = fmaf(fy, x10 - x00, x00);
                        const float y1v = fmaf(fy, x11 - x01, x01);
                        sum += fmaf(fz, y1v - y0v, y0v);
                    } else {
                        const float gxw = 1.0f - fx, gyw = 1.0f - fy, gzw = 1.0f - fz;
                        sum += cornerf(vol, x0f,       y0f,       z0f,       gxw * gyw * gzw);
                        sum += cornerf(vol, x0f + 1.f, y0f,       z0f,       fx  * gyw * gzw);
                        sum += cornerf(vol, x0f,       y0f + 1.f, z0f,       gxw * fy  * gzw);
                        sum += cornerf(vol, x0f + 1.f, y0f + 1.f, z0f,       fx  * fy  * gzw);
                        sum += cornerf(vol, x0f,       y0f,       z0f + 1.f, gxw * gyw * fz);
                        sum += cornerf(vol, x0f + 1.f, y0f,       z0f + 1.f, fx  * gyw * fz);
                        sum += cornerf(vol, x0f,       y0f + 1.f, z0f + 1.f, gxw * fy  * fz);
                        sum += cornerf(vol, x0f + 1.f, y0f + 1.f, z0f + 1.f, fx  * fy  * fz);
                    }
                    ++sc;
                }
            }
        } else {
            // Direct-gather path (mode 0 / degenerate corner rays)
            #pragma unroll 4
            for (int s = 0; s < NS; ++s) {
                const float fs = (float)s;
                const float cx = fmaf(qx, fs, basex);
                const float cy = fmaf(qy, fs, basey);
                const float cz = fmaf(qz, fs, basez);
                const float x0 = floorf(cx), y0 = floorf(cy), z0 = floorf(cz);
                const float fx = cx - x0, fy = cy - y0, fz = cz - z0;
                const float gx = 1.0f - fx, gy = 1.0f - fy, gz = 1.0f - fz;

                if (x0 >= 0.f && x0 <= 126.f &&
                    y0 >= 0.f && y0 <= 126.f &&
                    z0 >= 0.f && z0 <= 126.f) {
                    const int base = (((int)z0) * RES + ((int)y0)) * RES + ((int)x0);
                    const float2 vA = load_f2(vol + base);
                    const float2 vB = load_f2(vol + base + RES);
                    const float2 vC = load_f2(vol + base + RES * RES);
                    const float2 vD = load_f2(vol + base + RES * RES + RES);
                    const float gygz = gy * gz, fygz = fy * gz;
                    const float gyfz = gy * fz, fyfz = fy * fz;
                    sum += (vA.x * gx + vA.y * fx) * gygz
                         + (vB.x * gx + vB.y * fx) * fygz
                         + (vC.x * gx + vC.y * fx) * gyfz
                         + (vD.x * gx + vD.y * fx) * fyfz;
                } else {
                    sum += cornerf(vol, x0,       y0,       z0,       gx * gy * gz);
                    sum += cornerf(vol, x0 + 1.f, y0,       z0,       fx * gy * gz);
                    sum += cornerf(vol, x0,       y0 + 1.f, z0,       gx * fy * gz);
                    sum += cornerf(vol, x0 + 1.f, y0 + 1.f, z0,       fx * fy * gz);
                    sum += cornerf(vol, x0,       y0,       z0 + 1.f, gx * gy * fz);
                    sum += cornerf(vol, x0 + 1.f, y0,       z0 + 1.f, fx * gy * fz);
                    sum += cornerf(vol, x0,       y0 + 1.f, z0 + 1.f, gx * fy * fz);
                    sum += cornerf(vol, x0 + 1.f, y0 + 1.f, z0 + 1.f, fx * fy * fz);
                }
            }
        }

        if (inImg) {
            const float delta = range * (1.0f / 64.0f);
            out[i * W + j] = valid ? sum * delta : 0.0f;
        }
    }
}

extern "C" void kernel_launch(void* const* d_in, const int* in_sizes, int n_in,
                              void* d_out, int out_size, void* d_ws, size_t ws_size,
                              hipStream_t stream) {
    const float* vol  = (const float*)d_in[0];
    const float* wvt  = (const float*)d_in[1];
    const float* proj = (const float*)d_in[2];
    const float* cam  = (const float*)d_in[3];
    const float* bbox = (const float*)d_in[4];
    const int*   pH   = (const int*)d_in[5];
    const int*   pW   = (const int*)d_in[6];
    const int*   pmode= (const int*)d_in[7];
    float* out = (float*)d_out;

    int blocks = (out_size + 255) / 256;
    if (blocks < 1) blocks = 1;
    dsv_render<<<blocks, 256, 0, stream>>>(vol, wvt, proj, cam, bbox, pH, pW, pmode, out);
}

// Round 12
// 123.005 us; speedup vs baseline: 1.4076x; 1.0680x over previous
//
#include <hip/hip_runtime.h>
#include <math.h>

#define RES 128
#define NS 64
#define EPSF 1e-8f
#define ZSL 8             // slab thickness (z voxels)
#define NSLAB (RES / ZSL) // 16
#define WXS 16            // staged lateral window x extent
#define WYS 16            // staged lateral window y extent
#define WROW 17           // padded row stride
#define ZPL 9             // staged z planes (ZSL + 1 shared face)

// Ladder: 86.7us direct-gather (L1 line-service bound, r3/r6/r9) ->
// 69.2us LDS-slab (r11). r11 residual: staging global latency exposed
// between barriers (VALUBusy 39%, grid-limited 4 blocks/CU). This round:
// T14 async-stage split — issue slab k+1's 9 loads into regs BEFORE
// consuming slab k; ds_write after the consumed-barrier. Latency hides
// under consume. Fallback cornerf path keeps correctness window-independent.

// General 4x4 inverse, Gauss-Jordan with partial pivoting, double internal.
__device__ void inv4x4(const float* __restrict__ A, double out[4][4]) {
    double m[4][8];
    for (int r = 0; r < 4; ++r) {
        for (int c = 0; c < 4; ++c) {
            m[r][c]     = (double)A[r * 4 + c];
            m[r][c + 4] = (r == c) ? 1.0 : 0.0;
        }
    }
    for (int col = 0; col < 4; ++col) {
        int piv = col;
        double best = fabs(m[col][col]);
        for (int r = col + 1; r < 4; ++r) {
            double v = fabs(m[r][col]);
            if (v > best) { best = v; piv = r; }
        }
        if (piv != col) {
            for (int c = 0; c < 8; ++c) {
                double t = m[col][c]; m[col][c] = m[piv][c]; m[piv][c] = t;
            }
        }
        double inv = 1.0 / m[col][col];
        for (int c = 0; c < 8; ++c) m[col][c] *= inv;
        for (int r = 0; r < 4; ++r) {
            if (r == col) continue;
            double f = m[r][col];
            for (int c = 0; c < 8; ++c) m[r][c] -= f * m[col][c];
        }
    }
    for (int r = 0; r < 4; ++r)
        for (int c = 0; c < 4; ++c)
            out[r][c] = m[r][c + 4];
}

// 8-byte pair load from a 4-byte-aligned address, without UB.
__device__ __forceinline__ float2 load_f2(const float* __restrict__ p) {
    float2 r;
    __builtin_memcpy(&r, p, 8);
    return r;
}

// Zero-padding corner fetch; NaN-safe (NaN coords fail the tests -> 0).
__device__ __forceinline__ float cornerf(const float* __restrict__ vol,
                                         float xf, float yf, float zf, float w) {
    if (xf >= 0.f && xf <= 127.f &&
        yf >= 0.f && yf <= 127.f &&
        zf >= 0.f && zf <= 127.f) {
        int xi = (int)xf, yi = (int)yf, zi = (int)zf;
        return vol[(zi * RES + yi) * RES + xi] * w;
    }
    return 0.f;
}

__global__ __launch_bounds__(256) void dsv_render(
    const float* __restrict__ vol,
    const float* __restrict__ wvt,
    const float* __restrict__ proj,
    const float* __restrict__ cam,
    const float* __restrict__ bbox,
    const int*   __restrict__ pH,
    const int*   __restrict__ pW,
    const int*   __restrict__ pmode,
    float*       __restrict__ out)
{
    __shared__ float sC[28];
    __shared__ float crp[4][6];            // 4 tile-corner rays: base.xyz, q.xyz
    __shared__ int   win[NSLAB][2];        // per-slab window origin (wx0, wy0)
    __shared__ float slab[ZPL][WYS][WROW]; // staged volume window (~9.6 KB)

    const int H = pH[0];
    const int W = pW[0];
    const int mode = pmode[0];

    if (threadIdx.x == 0) {
        double vi[4][4], pinv[4][4];
        inv4x4(wvt, vi);
        inv4x4(proj, pinv);
        for (int i = 0; i < 4; ++i) {
            for (int j = 0; j < 4; ++j) {
                double s = 0.0;
                for (int k = 0; k < 4; ++k) s += pinv[i][k] * vi[k][j];
                sC[i * 4 + j] = (float)s;
            }
        }
        float bminx = bbox[0], bminy = bbox[1], bminz = bbox[2];
        float bmaxx = bbox[3], bmaxy = bbox[4], bmaxz = bbox[5];
        float ex = bmaxx - bminx, ey = bmaxy - bminy, ez = bmaxz - bminz;
        float ddx = -(float)vi[2][0], ddy = -(float)vi[2][1], ddz = -(float)vi[2][2];
        float nn = sqrtf(ddx * ddx + ddy * ddy + ddz * ddz) + EPSF;
        ddx /= nn; ddy /= nn; ddz /= nn;
        float diag = sqrtf(ex * ex + ey * ey + ez * ez);
        sC[16] = ddx; sC[17] = ddy; sC[18] = ddz;
        sC[19] = (float)vi[0][0] * ex * 0.5f;
        sC[20] = (float)vi[0][1] * ex * 0.5f;
        sC[21] = (float)vi[0][2] * ex * 0.5f;
        sC[22] = (float)vi[1][0] * ey * 0.5f;
        sC[23] = (float)vi[1][1] * ey * 0.5f;
        sC[24] = (float)vi[1][2] * ey * 0.5f;
        sC[25] = (bminx + bmaxx) * 0.5f - ddx * diag * 0.5f;
        sC[26] = (bminy + bmaxy) * 0.5f - ddy * diag * 0.5f;
        sC[27] = (bminz + bmaxz) * 0.5f - ddz * diag * 0.5f;
    }
    __syncthreads();

    const float bminx = bbox[0], bminy = bbox[1], bminz = bbox[2];
    const float bmaxx = bbox[3], bmaxy = bbox[4], bmaxz = bbox[5];
    const float kx = 127.0f / (bmaxx - bminx + EPSF);
    const float ky = 127.0f / (bmaxy - bminy + EPSF);
    const float kz = 127.0f / (bmaxz - bminz + EPSF);
    const float camx = cam[0], camy = cam[1], camz = cam[2];

    const int nTx = (W + 15) >> 4;
    const int nTy = (H + 15) >> 4;
    const int nTiles = nTx * nTy;
    const int tid = (int)threadIdx.x;
    const int tx = tid & 15;
    const int ty = tid >> 4;

    for (int tile = blockIdx.x; tile < nTiles; tile += gridDim.x) {
        const int ti = tile / nTx;
        const int tj = tile - ti * nTx;
        const int i = ti * 16 + ty;
        const int j = tj * 16 + tx;
        const bool inImg = (i < H) && (j < W);

        const float nx = (float)j / (float)(W - 1) * 2.0f - 1.0f;
        const float ny = (float)i / (float)(H - 1) * 2.0f - 1.0f;

        float ox, oy, oz, dx, dy, dz;
        if (mode == 0) {
            dx = sC[16]; dy = sC[17]; dz = sC[18];
            ox = sC[25] + nx * sC[19] + ny * sC[22];
            oy = sC[26] + nx * sC[20] + ny * sC[23];
            oz = sC[27] + nx * sC[21] + ny * sC[24];
        } else {
            float wx = nx * sC[0] + ny * sC[4] + sC[8]  + sC[12];
            float wy = nx * sC[1] + ny * sC[5] + sC[9]  + sC[13];
            float wz = nx * sC[2] + ny * sC[6] + sC[10] + sC[14];
            float ww = nx * sC[3] + ny * sC[7] + sC[11] + sC[15];
            float invw = 1.0f / (ww + EPSF);
            wx *= invw; wy *= invw; wz *= invw;
            ox = camx; oy = camy; oz = camz;
            dx = wx - ox; dy = wy - oy; dz = wz - oz;
            float n = sqrtf(dx * dx + dy * dy + dz * dz) + EPSF;
            dx /= n; dy /= n; dz /= n;
        }

        // AABB slab test (with reference's +EPS on dir)
        const float ix = 1.0f / (dx + EPSF);
        const float iy = 1.0f / (dy + EPSF);
        const float iz = 1.0f / (dz + EPSF);
        float t1 = (bminx - ox) * ix, t2 = (bmaxx - ox) * ix;
        float tn = fminf(t1, t2), tf = fmaxf(t1, t2);
        t1 = (bminy - oy) * iy; t2 = (bmaxy - oy) * iy;
        tn = fmaxf(tn, fminf(t1, t2)); tf = fminf(tf, fmaxf(t1, t2));
        t1 = (bminz - oz) * iz; t2 = (bmaxz - oz) * iz;
        tn = fmaxf(tn, fminf(t1, t2)); tf = fminf(tf, fmaxf(t1, t2));
        tn = fmaxf(tn, 0.0f);
        const bool valid = tf > tn;
        const float range = tf - tn;

        // Per-ray affine into voxel space: c(s) = base + q * s, s = 0..63
        const float sdx = dx * kx, sdy = dy * ky, sdz = dz * kz;
        const float basex = fmaf(sdx, tn, (ox - bminx) * kx);
        const float basey = fmaf(sdy, tn, (oy - bminy) * ky);
        const float basez = fmaf(sdz, tn, (oz - bminz) * kz);
        const float r63 = range * (1.0f / 63.0f);
        const float qx = sdx * r63, qy = sdy * r63, qz = sdz * r63;

        // Publish tile-corner rays (pixels (0,0),(0,15),(15,0),(15,15))
        int cidx = -1;
        if      (tid == 0)   cidx = 0;
        else if (tid == 15)  cidx = 1;
        else if (tid == 240) cidx = 2;
        else if (tid == 255) cidx = 3;
        if (cidx >= 0) {
            crp[cidx][0] = basex; crp[cidx][1] = basey; crp[cidx][2] = basez;
            crp[cidx][3] = qx;    crp[cidx][4] = qy;    crp[cidx][5] = qz;
        }
        __syncthreads();

        const bool ok = (mode != 0)
            && fabsf(crp[0][5]) > 1e-4f && fabsf(crp[1][5]) > 1e-4f
            && fabsf(crp[2][5]) > 1e-4f && fabsf(crp[3][5]) > 1e-4f;

        float sum = 0.0f;

        if (ok) {
            // Per-slab lateral window from the 4 corner ray LINES at the
            // slab's bounding z-planes (bounds all tile rays at fixed z).
            if (tid < NSLAB) {
                const float z0p = (float)(tid * ZSL);
                const float z1p = (float)(tid * ZSL + ZSL);
                float mnx = 1e30f, mny = 1e30f;
                #pragma unroll
                for (int c = 0; c < 4; ++c) {
                    const float bx = crp[c][0], by = crp[c][1], bz = crp[c][2];
                    const float cqx = crp[c][3], cqy = crp[c][4], cqz = crp[c][5];
                    const float iq = 1.0f / cqz;
                    const float s0 = (z0p - bz) * iq;
                    const float s1 = (z1p - bz) * iq;
                    const float xa = fmaf(cqx, s0, bx), xb = fmaf(cqx, s1, bx);
                    const float ya = fmaf(cqy, s0, by), yb = fmaf(cqy, s1, by);
                    mnx = fminf(mnx, fminf(xa, xb));
                    mny = fminf(mny, fminf(ya, yb));
                }
                mnx = fminf(fmaxf(mnx, -1e6f), 1e6f);
                mny = fminf(fmaxf(mny, -1e6f), 1e6f);
                win[tid][0] = (int)floorf(mnx) - 1;
                win[tid][1] = (int)floorf(mny) - 1;
            }
            __syncthreads();   // win[] ready

            // --- Async-stage pipeline (T14): regs -> LDS, issue-early ---
            float rv[ZPL];

            // Prologue: stage slab 0
            {
                const int wx0 = win[0][0], wy0 = win[0][1];
                const int gx = wx0 + tx, gy = wy0 + ty;
                const bool lat = ((unsigned)gx < RES) && ((unsigned)gy < RES);
                unsigned gaddr = (unsigned)((gy * RES) + gx);
                #pragma unroll
                for (int z = 0; z < ZPL; ++z) {
                    rv[z] = (lat && z < RES) ? vol[gaddr] : 0.0f;
                    gaddr += RES * RES;
                }
                #pragma unroll
                for (int z = 0; z < ZPL; ++z) slab[z][ty][tx] = rv[z];
            }
            __syncthreads();   // slab 0 ready

            int sc = 0;
            for (int k = 0; k < NSLAB; ++k) {
                const int wx0 = win[k][0];
                const int wy0 = win[k][1];
                const int zk  = k * ZSL;

                // Issue next slab's loads EARLY (hide latency under consume)
                if (k + 1 < NSLAB) {
                    const int nzk = zk + ZSL;
                    const int nwx0 = win[k + 1][0], nwy0 = win[k + 1][1];
                    const int gx = nwx0 + tx, gy = nwy0 + ty;
                    const bool lat = ((unsigned)gx < RES) && ((unsigned)gy < RES);
                    unsigned gaddr = (unsigned)(((nzk) * RES + gy) * RES + gx);
                    #pragma unroll
                    for (int z = 0; z < ZPL; ++z) {
                        rv[z] = (lat && (nzk + z) < RES) ? vol[gaddr] : 0.0f;
                        gaddr += RES * RES;
                    }
                }

                const float zend = (k == NSLAB - 1) ? 1e30f : (float)(zk + ZSL);

                while (sc < NS) {
                    const float fs = (float)sc;
                    const float cz = fmaf(qz, fs, basez);
                    if (!(cz < zend)) break;   // NaN -> break (0 contribution)
                    const float cx = fmaf(qx, fs, basex);
                    const float cy = fmaf(qy, fs, basey);
                    const float x0f = floorf(cx), y0f = floorf(cy), z0f = floorf(cz);
                    const float fx = cx - x0f, fy = cy - y0f, fz = cz - z0f;
                    const int ix0 = (int)x0f, iy0 = (int)y0f, iz0 = (int)z0f;

                    if ((unsigned)(ix0 - wx0) <= (unsigned)(WXS - 2) &&
                        (unsigned)(iy0 - wy0) <= (unsigned)(WYS - 2) &&
                        (unsigned)(iz0 - zk)  <= (unsigned)(ZSL - 1) &&
                        x0f == x0f) {
                        const int lx = ix0 - wx0;
                        const int ly = iy0 - wy0;
                        const int lz = iz0 - zk;
                        const float* p = &slab[lz][ly][lx];
                        const float2 A0 = load_f2(p);
                        const float2 A1 = load_f2(p + WROW);
                        const float2 B0 = load_f2(p + WYS * WROW);
                        const float2 B1 = load_f2(p + WYS * WROW + WROW);
                        const float x00 = fmaf(fx, A0.y - A0.x, A0.x);
                        const float x10 = fmaf(fx, A1.y - A1.x, A1.x);
                        const float x01 = fmaf(fx, B0.y - B0.x, B0.x);
                        const float x11 = fmaf(fx, B1.y - B1.x, B1.x);
                        const float y0v = fmaf(fy, x10 - x00, x00);
                        const float y1v = fmaf(fy, x11 - x01, x01);
                        sum += fmaf(fz, y1v - y0v, y0v);
                    } else {
                        const float gxw = 1.0f - fx, gyw = 1.0f - fy, gzw = 1.0f - fz;
                        sum += cornerf(vol, x0f,       y0f,       z0f,       gxw * gyw * gzw);
                        sum += cornerf(vol, x0f + 1.f, y0f,       z0f,       fx  * gyw * gzw);
                        sum += cornerf(vol, x0f,       y0f + 1.f, z0f,       gxw * fy  * gzw);
                        sum += cornerf(vol, x0f + 1.f, y0f + 1.f, z0f,       fx  * fy  * gzw);
                        sum += cornerf(vol, x0f,       y0f,       z0f + 1.f, gxw * gyw * fz);
                        sum += cornerf(vol, x0f + 1.f, y0f,       z0f + 1.f, fx  * gyw * fz);
                        sum += cornerf(vol, x0f,       y0f + 1.f, z0f + 1.f, gxw * fy  * fz);
                        sum += cornerf(vol, x0f + 1.f, y0f + 1.f, z0f + 1.f, fx  * fy  * fz);
                    }
                    ++sc;
                }

                __syncthreads();   // slab k fully consumed by all waves
                if (k + 1 < NSLAB) {
                    #pragma unroll
                    for (int z = 0; z < ZPL; ++z) slab[z][ty][tx] = rv[z];
                    __syncthreads();   // slab k+1 ready
                }
            }
        } else {
            // Direct-gather path (mode 0 / degenerate corner rays)
            #pragma unroll 4
            for (int s = 0; s < NS; ++s) {
                const float fs = (float)s;
                const float cx = fmaf(qx, fs, basex);
                const float cy = fmaf(qy, fs, basey);
                const float cz = fmaf(qz, fs, basez);
                const float x0 = floorf(cx), y0 = floorf(cy), z0 = floorf(cz);
                const float fx = cx - x0, fy = cy - y0, fz = cz - z0;
                const float gx = 1.0f - fx, gy = 1.0f - fy, gz = 1.0f - fz;

                if (x0 >= 0.f && x0 <= 126.f &&
                    y0 >= 0.f && y0 <= 126.f &&
                    z0 >= 0.f && z0 <= 126.f) {
                    const int base = (((int)z0) * RES + ((int)y0)) * RES + ((int)x0);
                    const float2 vA = load_f2(vol + base);
                    const float2 vB = load_f2(vol + base + RES);
                    const float2 vC = load_f2(vol + base + RES * RES);
                    const float2 vD = load_f2(vol + base + RES * RES + RES);
                    const float gygz = gy * gz, fygz = fy * gz;
                    const float gyfz = gy * fz, fyfz = fy * fz;
                    sum += (vA.x * gx + vA.y * fx) * gygz
                         + (vB.x * gx + vB.y * fx) * fygz
                         + (vC.x * gx + vC.y * fx) * gyfz
                         + (vD.x * gx + vD.y * fx) * fyfz;
                } else {
                    sum += cornerf(vol, x0,       y0,       z0,       gx * gy * gz);
                    sum += cornerf(vol, x0 + 1.f, y0,       z0,       fx * gy * gz);
                    sum += cornerf(vol, x0,       y0 + 1.f, z0,       gx * fy * gz);
                    sum += cornerf(vol, x0 + 1.f, y0 + 1.f, z0,       fx * fy * gz);
                    sum += cornerf(vol, x0,       y0,       z0 + 1.f, gx * gy * fz);
                    sum += cornerf(vol, x0 + 1.f, y0,       z0 + 1.f, fx * gy * fz);
                    sum += cornerf(vol, x0,       y0 + 1.f, z0 + 1.f, gx * fy * fz);
                    sum += cornerf(vol, x0 + 1.f, y0 + 1.f, z0 + 1.f, fx * fy * fz);
                }
            }
        }

        if (inImg) {
            const float delta = range * (1.0f / 64.0f);
            out[i * W + j] = valid ? sum * delta : 0.0f;
        }
    }
}

extern "C" void kernel_launch(void* const* d_in, const int* in_sizes, int n_in,
                              void* d_out, int out_size, void* d_ws, size_t ws_size,
                              hipStream_t stream) {
    const float* vol  = (const float*)d_in[0];
    const float* wvt  = (const float*)d_in[1];
    const float* proj = (const float*)d_in[2];
    const float* cam  = (const float*)d_in[3];
    const float* bbox = (const float*)d_in[4];
    const int*   pH   = (const int*)d_in[5];
    const int*   pW   = (const int*)d_in[6];
    const int*   pmode= (const int*)d_in[7];
    float* out = (float*)d_out;

    int blocks = (out_size + 255) / 256;
    if (blocks < 1) blocks = 1;
    dsv_render<<<blocks, 256, 0, stream>>>(vol, wvt, proj, cam, bbox, pH, pW, pmode, out);
}

// Round 13
// 119.518 us; speedup vs baseline: 1.4486x; 1.0292x over previous
//
#include <hip/hip_runtime.h>
#include <math.h>

#define RES 128
#define NS 64
#define EPSF 1e-8f
#define ZSL 8             // slab thickness (z voxels)
#define NSLAB (RES / ZSL) // 16
#define WXS 16            // staged lateral window x extent
#define WYS 16            // staged lateral window y extent
#define WROW 17           // padded row stride
#define ZPL 9             // staged z planes (ZSL + 1 shared face)

// Ladder: 86.7us direct-gather (L1 line-service bound, r3/r6/r9) -> 69.2us
// LDS-slab (r11) -> 68.2us (+T14, ~null, r12). r12 lesson: stall is not
// staging latency; it's 31 barriers/tile + unpipelined while-break consume.
// This round: LDS double-buffer (16 barriers) + closed-form counted consume
// loop (unroll-2, compiler can overlap ds_read with FMA chain). Off-by-one
// in the count is safe: mis-assigned samples fail the window check and take
// the global cornerf fallback.

// General 4x4 inverse, Gauss-Jordan with partial pivoting, double internal.
__device__ void inv4x4(const float* __restrict__ A, double out[4][4]) {
    double m[4][8];
    for (int r = 0; r < 4; ++r) {
        for (int c = 0; c < 4; ++c) {
            m[r][c]     = (double)A[r * 4 + c];
            m[r][c + 4] = (r == c) ? 1.0 : 0.0;
        }
    }
    for (int col = 0; col < 4; ++col) {
        int piv = col;
        double best = fabs(m[col][col]);
        for (int r = col + 1; r < 4; ++r) {
            double v = fabs(m[r][col]);
            if (v > best) { best = v; piv = r; }
        }
        if (piv != col) {
            for (int c = 0; c < 8; ++c) {
                double t = m[col][c]; m[col][c] = m[piv][c]; m[piv][c] = t;
            }
        }
        double inv = 1.0 / m[col][col];
        for (int c = 0; c < 8; ++c) m[col][c] *= inv;
        for (int r = 0; r < 4; ++r) {
            if (r == col) continue;
            double f = m[r][col];
            for (int c = 0; c < 8; ++c) m[r][c] -= f * m[col][c];
        }
    }
    for (int r = 0; r < 4; ++r)
        for (int c = 0; c < 4; ++c)
            out[r][c] = m[r][c + 4];
}

// 8-byte pair load from a 4-byte-aligned address, without UB.
__device__ __forceinline__ float2 load_f2(const float* __restrict__ p) {
    float2 r;
    __builtin_memcpy(&r, p, 8);
    return r;
}

// Zero-padding corner fetch; NaN-safe (NaN coords fail the tests -> 0).
__device__ __forceinline__ float cornerf(const float* __restrict__ vol,
                                         float xf, float yf, float zf, float w) {
    if (xf >= 0.f && xf <= 127.f &&
        yf >= 0.f && yf <= 127.f &&
        zf >= 0.f && zf <= 127.f) {
        int xi = (int)xf, yi = (int)yf, zi = (int)zf;
        return vol[(zi * RES + yi) * RES + xi] * w;
    }
    return 0.f;
}

__global__ __launch_bounds__(256) void dsv_render(
    const float* __restrict__ vol,
    const float* __restrict__ wvt,
    const float* __restrict__ proj,
    const float* __restrict__ cam,
    const float* __restrict__ bbox,
    const int*   __restrict__ pH,
    const int*   __restrict__ pW,
    const int*   __restrict__ pmode,
    float*       __restrict__ out)
{
    __shared__ float sC[28];
    __shared__ float crp[4][6];               // 4 tile-corner rays: base.xyz, q.xyz
    __shared__ int   win[NSLAB][2];           // per-slab window origin (wx0, wy0)
    __shared__ float slab[2][ZPL][WYS][WROW]; // double-buffered window (~19 KB)

    const int H = pH[0];
    const int W = pW[0];
    const int mode = pmode[0];

    if (threadIdx.x == 0) {
        double vi[4][4], pinv[4][4];
        inv4x4(wvt, vi);
        inv4x4(proj, pinv);
        for (int i = 0; i < 4; ++i) {
            for (int j = 0; j < 4; ++j) {
                double s = 0.0;
                for (int k = 0; k < 4; ++k) s += pinv[i][k] * vi[k][j];
                sC[i * 4 + j] = (float)s;
            }
        }
        float bminx = bbox[0], bminy = bbox[1], bminz = bbox[2];
        float bmaxx = bbox[3], bmaxy = bbox[4], bmaxz = bbox[5];
        float ex = bmaxx - bminx, ey = bmaxy - bminy, ez = bmaxz - bminz;
        float ddx = -(float)vi[2][0], ddy = -(float)vi[2][1], ddz = -(float)vi[2][2];
        float nn = sqrtf(ddx * ddx + ddy * ddy + ddz * ddz) + EPSF;
        ddx /= nn; ddy /= nn; ddz /= nn;
        float diag = sqrtf(ex * ex + ey * ey + ez * ez);
        sC[16] = ddx; sC[17] = ddy; sC[18] = ddz;
        sC[19] = (float)vi[0][0] * ex * 0.5f;
        sC[20] = (float)vi[0][1] * ex * 0.5f;
        sC[21] = (float)vi[0][2] * ex * 0.5f;
        sC[22] = (float)vi[1][0] * ey * 0.5f;
        sC[23] = (float)vi[1][1] * ey * 0.5f;
        sC[24] = (float)vi[1][2] * ey * 0.5f;
        sC[25] = (bminx + bmaxx) * 0.5f - ddx * diag * 0.5f;
        sC[26] = (bminy + bmaxy) * 0.5f - ddy * diag * 0.5f;
        sC[27] = (bminz + bmaxz) * 0.5f - ddz * diag * 0.5f;
    }
    __syncthreads();

    const float bminx = bbox[0], bminy = bbox[1], bminz = bbox[2];
    const float bmaxx = bbox[3], bmaxy = bbox[4], bmaxz = bbox[5];
    const float kx = 127.0f / (bmaxx - bminx + EPSF);
    const float ky = 127.0f / (bmaxy - bminy + EPSF);
    const float kz = 127.0f / (bmaxz - bminz + EPSF);
    const float camx = cam[0], camy = cam[1], camz = cam[2];

    const int nTx = (W + 15) >> 4;
    const int nTy = (H + 15) >> 4;
    const int nTiles = nTx * nTy;
    const int tid = (int)threadIdx.x;
    const int tx = tid & 15;
    const int ty = tid >> 4;

    for (int tile = blockIdx.x; tile < nTiles; tile += gridDim.x) {
        const int ti = tile / nTx;
        const int tj = tile - ti * nTx;
        const int i = ti * 16 + ty;
        const int j = tj * 16 + tx;
        const bool inImg = (i < H) && (j < W);

        const float nx = (float)j / (float)(W - 1) * 2.0f - 1.0f;
        const float ny = (float)i / (float)(H - 1) * 2.0f - 1.0f;

        float ox, oy, oz, dx, dy, dz;
        if (mode == 0) {
            dx = sC[16]; dy = sC[17]; dz = sC[18];
            ox = sC[25] + nx * sC[19] + ny * sC[22];
            oy = sC[26] + nx * sC[20] + ny * sC[23];
            oz = sC[27] + nx * sC[21] + ny * sC[24];
        } else {
            float wx = nx * sC[0] + ny * sC[4] + sC[8]  + sC[12];
            float wy = nx * sC[1] + ny * sC[5] + sC[9]  + sC[13];
            float wz = nx * sC[2] + ny * sC[6] + sC[10] + sC[14];
            float ww = nx * sC[3] + ny * sC[7] + sC[11] + sC[15];
            float invw = 1.0f / (ww + EPSF);
            wx *= invw; wy *= invw; wz *= invw;
            ox = camx; oy = camy; oz = camz;
            dx = wx - ox; dy = wy - oy; dz = wz - oz;
            float n = sqrtf(dx * dx + dy * dy + dz * dz) + EPSF;
            dx /= n; dy /= n; dz /= n;
        }

        // AABB slab test (with reference's +EPS on dir)
        const float ix = 1.0f / (dx + EPSF);
        const float iy = 1.0f / (dy + EPSF);
        const float iz = 1.0f / (dz + EPSF);
        float t1 = (bminx - ox) * ix, t2 = (bmaxx - ox) * ix;
        float tn = fminf(t1, t2), tf = fmaxf(t1, t2);
        t1 = (bminy - oy) * iy; t2 = (bmaxy - oy) * iy;
        tn = fmaxf(tn, fminf(t1, t2)); tf = fminf(tf, fmaxf(t1, t2));
        t1 = (bminz - oz) * iz; t2 = (bmaxz - oz) * iz;
        tn = fmaxf(tn, fminf(t1, t2)); tf = fminf(tf, fmaxf(t1, t2));
        tn = fmaxf(tn, 0.0f);
        const bool valid = tf > tn;
        const float range = tf - tn;

        // Per-ray affine into voxel space: c(s) = base + q * s, s = 0..63
        const float sdx = dx * kx, sdy = dy * ky, sdz = dz * kz;
        const float basex = fmaf(sdx, tn, (ox - bminx) * kx);
        const float basey = fmaf(sdy, tn, (oy - bminy) * ky);
        const float basez = fmaf(sdz, tn, (oz - bminz) * kz);
        const float r63 = range * (1.0f / 63.0f);
        const float qx = sdx * r63, qy = sdy * r63, qz = sdz * r63;

        // Publish tile-corner rays (pixels (0,0),(0,15),(15,0),(15,15))
        int cidx = -1;
        if      (tid == 0)   cidx = 0;
        else if (tid == 15)  cidx = 1;
        else if (tid == 240) cidx = 2;
        else if (tid == 255) cidx = 3;
        if (cidx >= 0) {
            crp[cidx][0] = basex; crp[cidx][1] = basey; crp[cidx][2] = basez;
            crp[cidx][3] = qx;    crp[cidx][4] = qy;    crp[cidx][5] = qz;
        }
        __syncthreads();

        const bool ok = (mode != 0)
            && fabsf(crp[0][5]) > 1e-4f && fabsf(crp[1][5]) > 1e-4f
            && fabsf(crp[2][5]) > 1e-4f && fabsf(crp[3][5]) > 1e-4f;

        float sum = 0.0f;

        if (ok) {
            // Per-slab lateral window from the 4 corner ray LINES at the
            // slab's bounding z-planes (bounds all tile rays at fixed z).
            if (tid < NSLAB) {
                const float z0p = (float)(tid * ZSL);
                const float z1p = (float)(tid * ZSL + ZSL);
                float mnx = 1e30f, mny = 1e30f;
                #pragma unroll
                for (int c = 0; c < 4; ++c) {
                    const float bx = crp[c][0], by = crp[c][1], bz = crp[c][2];
                    const float cqx = crp[c][3], cqy = crp[c][4], cqz = crp[c][5];
                    const float iq = 1.0f / cqz;
                    const float s0 = (z0p - bz) * iq;
                    const float s1 = (z1p - bz) * iq;
                    const float xa = fmaf(cqx, s0, bx), xb = fmaf(cqx, s1, bx);
                    const float ya = fmaf(cqy, s0, by), yb = fmaf(cqy, s1, by);
                    mnx = fminf(mnx, fminf(xa, xb));
                    mny = fminf(mny, fminf(ya, yb));
                }
                mnx = fminf(fmaxf(mnx, -1e6f), 1e6f);
                mny = fminf(fmaxf(mny, -1e6f), 1e6f);
                win[tid][0] = (int)floorf(mnx) - 1;
                win[tid][1] = (int)floorf(mny) - 1;
            }
            __syncthreads();   // win[] ready

            float rv[ZPL];

            // Prologue: stage slab 0 into buffer 0
            {
                const int wx0 = win[0][0], wy0 = win[0][1];
                const int gx = wx0 + tx, gy = wy0 + ty;
                const bool lat = ((unsigned)gx < RES) && ((unsigned)gy < RES);
                unsigned gaddr = (unsigned)((gy * RES) + gx);
                #pragma unroll
                for (int z = 0; z < ZPL; ++z) {
                    rv[z] = (lat && z < RES) ? vol[gaddr] : 0.0f;
                    gaddr += RES * RES;
                }
                #pragma unroll
                for (int z = 0; z < ZPL; ++z) slab[0][z][ty][tx] = rv[z];
            }
            __syncthreads();   // slab 0 ready

            int sc = 0;
            for (int k = 0; k < NSLAB; ++k) {
                const int cur = k & 1;
                const int wx0 = win[k][0];
                const int wy0 = win[k][1];
                const int zk  = k * ZSL;

                // Issue next slab's loads EARLY (hide under consume)
                if (k + 1 < NSLAB) {
                    const int nzk = zk + ZSL;
                    const int nwx0 = win[k + 1][0], nwy0 = win[k + 1][1];
                    const int gx = nwx0 + tx, gy = nwy0 + ty;
                    const bool lat = ((unsigned)gx < RES) && ((unsigned)gy < RES);
                    unsigned gaddr = (unsigned)(((nzk) * RES + gy) * RES + gx);
                    #pragma unroll
                    for (int z = 0; z < ZPL; ++z) {
                        rv[z] = (lat && (nzk + z) < RES) ? vol[gaddr] : 0.0f;
                        gaddr += RES * RES;
                    }
                }

                const float zend = (k == NSLAB - 1) ? 1e30f : (float)(zk + ZSL);

                // Closed-form sample count for this slab (off-by-one safe:
                // misassigned samples fail the window check -> cornerf).
                int sc_end;
                if (qz > 1e-9f) {
                    sc_end = (int)ceilf((zend - basez) / qz);
                    if (sc_end < sc) sc_end = sc;
                    if (sc_end > NS) sc_end = NS;
                } else {
                    sc_end = (fmaf(qz, (float)sc, basez) < zend) ? NS : sc;
                }

                #pragma unroll 2
                for (int s = sc; s < sc_end; ++s) {
                    const float fs = (float)s;
                    const float cz = fmaf(qz, fs, basez);
                    const float cx = fmaf(qx, fs, basex);
                    const float cy = fmaf(qy, fs, basey);
                    const float x0f = floorf(cx), y0f = floorf(cy), z0f = floorf(cz);
                    const float fx = cx - x0f, fy = cy - y0f, fz = cz - z0f;
                    const int ix0 = (int)x0f, iy0 = (int)y0f, iz0 = (int)z0f;

                    if ((unsigned)(ix0 - wx0) <= (unsigned)(WXS - 2) &&
                        (unsigned)(iy0 - wy0) <= (unsigned)(WYS - 2) &&
                        (unsigned)(iz0 - zk)  <= (unsigned)(ZSL - 1) &&
                        x0f == x0f) {
                        const int lx = ix0 - wx0;
                        const int ly = iy0 - wy0;
                        const int lz = iz0 - zk;
                        const float* p = &slab[cur][lz][ly][lx];
                        const float2 A0 = load_f2(p);
                        const float2 A1 = load_f2(p + WROW);
                        const float2 B0 = load_f2(p + WYS * WROW);
                        const float2 B1 = load_f2(p + WYS * WROW + WROW);
                        const float x00 = fmaf(fx, A0.y - A0.x, A0.x);
                        const float x10 = fmaf(fx, A1.y - A1.x, A1.x);
                        const float x01 = fmaf(fx, B0.y - B0.x, B0.x);
                        const float x11 = fmaf(fx, B1.y - B1.x, B1.x);
                        const float y0v = fmaf(fy, x10 - x00, x00);
                        const float y1v = fmaf(fy, x11 - x01, x01);
                        sum += fmaf(fz, y1v - y0v, y0v);
                    } else {
                        const float gxw = 1.0f - fx, gyw = 1.0f - fy, gzw = 1.0f - fz;
                        sum += cornerf(vol, x0f,       y0f,       z0f,       gxw * gyw * gzw);
                        sum += cornerf(vol, x0f + 1.f, y0f,       z0f,       fx  * gyw * gzw);
                        sum += cornerf(vol, x0f,       y0f + 1.f, z0f,       gxw * fy  * gzw);
                        sum += cornerf(vol, x0f + 1.f, y0f + 1.f, z0f,       fx  * fy  * gzw);
                        sum += cornerf(vol, x0f,       y0f,       z0f + 1.f, gxw * gyw * fz);
                        sum += cornerf(vol, x0f + 1.f, y0f,       z0f + 1.f, fx  * gyw * fz);
                        sum += cornerf(vol, x0f,       y0f + 1.f, z0f + 1.f, gxw * fy  * fz);
                        sum += cornerf(vol, x0f + 1.f, y0f + 1.f, z0f + 1.f, fx  * fy  * fz);
                    }
                }
                sc = sc_end;

                // Write next slab to the other buffer; single barrier/slab.
                // Safe: barrier at end of iter k-1 guaranteed buf[cur^1]
                // (consumed at k-1) is no longer being read by any wave.
                if (k + 1 < NSLAB) {
                    #pragma unroll
                    for (int z = 0; z < ZPL; ++z) slab[cur ^ 1][z][ty][tx] = rv[z];
                    __syncthreads();   // slab k+1 ready
                }
            }
        } else {
            // Direct-gather path (mode 0 / degenerate corner rays)
            #pragma unroll 4
            for (int s = 0; s < NS; ++s) {
                const float fs = (float)s;
                const float cx = fmaf(qx, fs, basex);
                const float cy = fmaf(qy, fs, basey);
                const float cz = fmaf(qz, fs, basez);
                const float x0 = floorf(cx), y0 = floorf(cy), z0 = floorf(cz);
                const float fx = cx - x0, fy = cy - y0, fz = cz - z0;
                const float gx = 1.0f - fx, gy = 1.0f - fy, gz = 1.0f - fz;

                if (x0 >= 0.f && x0 <= 126.f &&
                    y0 >= 0.f && y0 <= 126.f &&
                    z0 >= 0.f && z0 <= 126.f) {
                    const int base = (((int)z0) * RES + ((int)y0)) * RES + ((int)x0);
                    const float2 vA = load_f2(vol + base);
                    const float2 vB = load_f2(vol + base + RES);
                    const float2 vC = load_f2(vol + base + RES * RES);
                    const float2 vD = load_f2(vol + base + RES * RES + RES);
                    const float gygz = gy * gz, fygz = fy * gz;
                    const float gyfz = gy * fz, fyfz = fy * fz;
                    sum += (vA.x * gx + vA.y * fx) * gygz
                         + (vB.x * gx + vB.y * fx) * fygz
                         + (vC.x * gx + vC.y * fx) * gyfz
                         + (vD.x * gx + vD.y * fx) * fyfz;
                } else {
                    sum += cornerf(vol, x0,       y0,       z0,       gx * gy * gz);
                    sum += cornerf(vol, x0 + 1.f, y0,       z0,       fx * gy * gz);
                    sum += cornerf(vol, x0,       y0 + 1.f, z0,       gx * fy * gz);
                    sum += cornerf(vol, x0 + 1.f, y0 + 1.f, z0,       fx * fy * gz);
                    sum += cornerf(vol, x0,       y0,       z0 + 1.f, gx * gy * fz);
                    sum += cornerf(vol, x0 + 1.f, y0,       z0 + 1.f, fx * gy * fz);
                    sum += cornerf(vol, x0,       y0 + 1.f, z0 + 1.f, gx * fy * fz);
                    sum += cornerf(vol, x0 + 1.f, y0 + 1.f, z0 + 1.f, fx * fy * fz);
                }
            }
        }

        if (inImg) {
            const float delta = range * (1.0f / 64.0f);
            out[i * W + j] = valid ? sum * delta : 0.0f;
        }
    }
}

extern "C" void kernel_launch(void* const* d_in, const int* in_sizes, int n_in,
                              void* d_out, int out_size, void* d_ws, size_t ws_size,
                              hipStream_t stream) {
    const float* vol  = (const float*)d_in[0];
    const float* wvt  = (const float*)d_in[1];
    const float* proj = (const float*)d_in[2];
    const float* cam  = (const float*)d_in[3];
    const float* bbox = (const float*)d_in[4];
    const int*   pH   = (const int*)d_in[5];
    const int*   pW   = (const int*)d_in[6];
    const int*   pmode= (const int*)d_in[7];
    float* out = (float*)d_out;

    int blocks = (out_size + 255) / 256;
    if (blocks < 1) blocks = 1;
    dsv_render<<<blocks, 256, 0, stream>>>(vol, wvt, proj, cam, bbox, pH, pW, pmode, out);
}

// Round 16
// 115.806 us; speedup vs baseline: 1.4951x; 1.0321x over previous
//
#include <hip/hip_runtime.h>
#include <math.h>

#define RES 128
#define NS 64
#define EPSF 1e-8f
#define ZSL 8             // slab thickness (z voxels)
#define NSLAB (RES / ZSL) // 16
#define WXS 16            // staged lateral window x extent
#define WYS 16            // staged lateral window y extent
#define WROW 17           // padded row stride
#define ZPL 9             // staged z planes (ZSL + 1 shared face)

// Ladder: 86.7us direct-gather (L1 line-service bound, r3/r6/r9) -> 69.2
// (LDS slab, r11) -> 68.2 (T14 ~null, r12) -> 55.3 (dbuf + counted loop,
// r13). r13 residual: dependency-latency-bound consume (no pipe >53%,
// ~10 waves/CU can't hide the 4xds_read + 7-FMA chain). This round:
// BRANCHLESS hot path — always lerp from clamped LDS indices, select via
// hit mask, rare cornerf fallback in an execz-skipped block. Lets unroll-2
// overlap sample s+1's LDS reads with sample s's FMA chain.

// General 4x4 inverse, Gauss-Jordan with partial pivoting, double internal.
__device__ void inv4x4(const float* __restrict__ A, double out[4][4]) {
    double m[4][8];
    for (int r = 0; r < 4; ++r) {
        for (int c = 0; c < 4; ++c) {
            m[r][c]     = (double)A[r * 4 + c];
            m[r][c + 4] = (r == c) ? 1.0 : 0.0;
        }
    }
    for (int col = 0; col < 4; ++col) {
        int piv = col;
        double best = fabs(m[col][col]);
        for (int r = col + 1; r < 4; ++r) {
            double v = fabs(m[r][col]);
            if (v > best) { best = v; piv = r; }
        }
        if (piv != col) {
            for (int c = 0; c < 8; ++c) {
                double t = m[col][c]; m[col][c] = m[piv][c]; m[piv][c] = t;
            }
        }
        double inv = 1.0 / m[col][col];
        for (int c = 0; c < 8; ++c) m[col][c] *= inv;
        for (int r = 0; r < 4; ++r) {
            if (r == col) continue;
            double f = m[r][col];
            for (int c = 0; c < 8; ++c) m[r][c] -= f * m[col][c];
        }
    }
    for (int r = 0; r < 4; ++r)
        for (int c = 0; c < 4; ++c)
            out[r][c] = m[r][c + 4];
}

// 8-byte pair load from a 4-byte-aligned address, without UB.
__device__ __forceinline__ float2 load_f2(const float* __restrict__ p) {
    float2 r;
    __builtin_memcpy(&r, p, 8);
    return r;
}

// Zero-padding corner fetch; NaN-safe (NaN coords fail the tests -> 0).
__device__ __forceinline__ float cornerf(const float* __restrict__ vol,
                                         float xf, float yf, float zf, float w) {
    if (xf >= 0.f && xf <= 127.f &&
        yf >= 0.f && yf <= 127.f &&
        zf >= 0.f && zf <= 127.f) {
        int xi = (int)xf, yi = (int)yf, zi = (int)zf;
        return vol[(zi * RES + yi) * RES + xi] * w;
    }
    return 0.f;
}

__device__ __forceinline__ int clampi(int v, int lo, int hi) {
    return v < lo ? lo : (v > hi ? hi : v);
}

__global__ __launch_bounds__(256) void dsv_render(
    const float* __restrict__ vol,
    const float* __restrict__ wvt,
    const float* __restrict__ proj,
    const float* __restrict__ cam,
    const float* __restrict__ bbox,
    const int*   __restrict__ pH,
    const int*   __restrict__ pW,
    const int*   __restrict__ pmode,
    float*       __restrict__ out)
{
    __shared__ float sC[28];
    __shared__ float crp[4][6];               // 4 tile-corner rays: base.xyz, q.xyz
    __shared__ int   win[NSLAB][2];           // per-slab window origin (wx0, wy0)
    __shared__ float slab[2][ZPL][WYS][WROW]; // double-buffered window (~19 KB)

    const int H = pH[0];
    const int W = pW[0];
    const int mode = pmode[0];

    if (threadIdx.x == 0) {
        double vi[4][4], pinv[4][4];
        inv4x4(wvt, vi);
        inv4x4(proj, pinv);
        for (int i = 0; i < 4; ++i) {
            for (int j = 0; j < 4; ++j) {
                double s = 0.0;
                for (int k = 0; k < 4; ++k) s += pinv[i][k] * vi[k][j];
                sC[i * 4 + j] = (float)s;
            }
        }
        float bminx = bbox[0], bminy = bbox[1], bminz = bbox[2];
        float bmaxx = bbox[3], bmaxy = bbox[4], bmaxz = bbox[5];
        float ex = bmaxx - bminx, ey = bmaxy - bminy, ez = bmaxz - bminz;
        float ddx = -(float)vi[2][0], ddy = -(float)vi[2][1], ddz = -(float)vi[2][2];
        float nn = sqrtf(ddx * ddx + ddy * ddy + ddz * ddz) + EPSF;
        ddx /= nn; ddy /= nn; ddz /= nn;
        float diag = sqrtf(ex * ex + ey * ey + ez * ez);
        sC[16] = ddx; sC[17] = ddy; sC[18] = ddz;
        sC[19] = (float)vi[0][0] * ex * 0.5f;
        sC[20] = (float)vi[0][1] * ex * 0.5f;
        sC[21] = (float)vi[0][2] * ex * 0.5f;
        sC[22] = (float)vi[1][0] * ey * 0.5f;
        sC[23] = (float)vi[1][1] * ey * 0.5f;
        sC[24] = (float)vi[1][2] * ey * 0.5f;
        sC[25] = (bminx + bmaxx) * 0.5f - ddx * diag * 0.5f;
        sC[26] = (bminy + bmaxy) * 0.5f - ddy * diag * 0.5f;
        sC[27] = (bminz + bmaxz) * 0.5f - ddz * diag * 0.5f;
    }
    __syncthreads();

    const float bminx = bbox[0], bminy = bbox[1], bminz = bbox[2];
    const float bmaxx = bbox[3], bmaxy = bbox[4], bmaxz = bbox[5];
    const float kx = 127.0f / (bmaxx - bminx + EPSF);
    const float ky = 127.0f / (bmaxy - bminy + EPSF);
    const float kz = 127.0f / (bmaxz - bminz + EPSF);
    const float camx = cam[0], camy = cam[1], camz = cam[2];

    const int nTx = (W + 15) >> 4;
    const int nTy = (H + 15) >> 4;
    const int nTiles = nTx * nTy;
    const int tid = (int)threadIdx.x;
    const int tx = tid & 15;
    const int ty = tid >> 4;

    for (int tile = blockIdx.x; tile < nTiles; tile += gridDim.x) {
        const int ti = tile / nTx;
        const int tj = tile - ti * nTx;
        const int i = ti * 16 + ty;
        const int j = tj * 16 + tx;
        const bool inImg = (i < H) && (j < W);

        const float nx = (float)j / (float)(W - 1) * 2.0f - 1.0f;
        const float ny = (float)i / (float)(H - 1) * 2.0f - 1.0f;

        float ox, oy, oz, dx, dy, dz;
        if (mode == 0) {
            dx = sC[16]; dy = sC[17]; dz = sC[18];
            ox = sC[25] + nx * sC[19] + ny * sC[22];
            oy = sC[26] + nx * sC[20] + ny * sC[23];
            oz = sC[27] + nx * sC[21] + ny * sC[24];
        } else {
            float wx = nx * sC[0] + ny * sC[4] + sC[8]  + sC[12];
            float wy = nx * sC[1] + ny * sC[5] + sC[9]  + sC[13];
            float wz = nx * sC[2] + ny * sC[6] + sC[10] + sC[14];
            float ww = nx * sC[3] + ny * sC[7] + sC[11] + sC[15];
            float invw = 1.0f / (ww + EPSF);
            wx *= invw; wy *= invw; wz *= invw;
            ox = camx; oy = camy; oz = camz;
            dx = wx - ox; dy = wy - oy; dz = wz - oz;
            float n = sqrtf(dx * dx + dy * dy + dz * dz) + EPSF;
            dx /= n; dy /= n; dz /= n;
        }

        // AABB slab test (with reference's +EPS on dir)
        const float ix = 1.0f / (dx + EPSF);
        const float iy = 1.0f / (dy + EPSF);
        const float iz = 1.0f / (dz + EPSF);
        float t1 = (bminx - ox) * ix, t2 = (bmaxx - ox) * ix;
        float tn = fminf(t1, t2), tf = fmaxf(t1, t2);
        t1 = (bminy - oy) * iy; t2 = (bmaxy - oy) * iy;
        tn = fmaxf(tn, fminf(t1, t2)); tf = fminf(tf, fmaxf(t1, t2));
        t1 = (bminz - oz) * iz; t2 = (bmaxz - oz) * iz;
        tn = fmaxf(tn, fminf(t1, t2)); tf = fminf(tf, fmaxf(t1, t2));
        tn = fmaxf(tn, 0.0f);
        const bool valid = tf > tn;
        const float range = tf - tn;

        // Per-ray affine into voxel space: c(s) = base + q * s, s = 0..63
        const float sdx = dx * kx, sdy = dy * ky, sdz = dz * kz;
        const float basex = fmaf(sdx, tn, (ox - bminx) * kx);
        const float basey = fmaf(sdy, tn, (oy - bminy) * ky);
        const float basez = fmaf(sdz, tn, (oz - bminz) * kz);
        const float r63 = range * (1.0f / 63.0f);
        const float qx = sdx * r63, qy = sdy * r63, qz = sdz * r63;

        // Publish tile-corner rays (pixels (0,0),(0,15),(15,0),(15,15))
        int cidx = -1;
        if      (tid == 0)   cidx = 0;
        else if (tid == 15)  cidx = 1;
        else if (tid == 240) cidx = 2;
        else if (tid == 255) cidx = 3;
        if (cidx >= 0) {
            crp[cidx][0] = basex; crp[cidx][1] = basey; crp[cidx][2] = basez;
            crp[cidx][3] = qx;    crp[cidx][4] = qy;    crp[cidx][5] = qz;
        }
        __syncthreads();

        const bool ok = (mode != 0)
            && fabsf(crp[0][5]) > 1e-4f && fabsf(crp[1][5]) > 1e-4f
            && fabsf(crp[2][5]) > 1e-4f && fabsf(crp[3][5]) > 1e-4f;

        float sum = 0.0f;

        if (ok) {
            // Per-slab lateral window from the 4 corner ray LINES at the
            // slab's bounding z-planes (bounds all tile rays at fixed z).
            if (tid < NSLAB) {
                const float z0p = (float)(tid * ZSL);
                const float z1p = (float)(tid * ZSL + ZSL);
                float mnx = 1e30f, mny = 1e30f;
                #pragma unroll
                for (int c = 0; c < 4; ++c) {
                    const float bx = crp[c][0], by = crp[c][1], bz = crp[c][2];
                    const float cqx = crp[c][3], cqy = crp[c][4], cqz = crp[c][5];
                    const float iq = 1.0f / cqz;
                    const float s0 = (z0p - bz) * iq;
                    const float s1 = (z1p - bz) * iq;
                    const float xa = fmaf(cqx, s0, bx), xb = fmaf(cqx, s1, bx);
                    const float ya = fmaf(cqy, s0, by), yb = fmaf(cqy, s1, by);
                    mnx = fminf(mnx, fminf(xa, xb));
                    mny = fminf(mny, fminf(ya, yb));
                }
                mnx = fminf(fmaxf(mnx, -1e6f), 1e6f);
                mny = fminf(fmaxf(mny, -1e6f), 1e6f);
                win[tid][0] = (int)floorf(mnx) - 1;
                win[tid][1] = (int)floorf(mny) - 1;
            }
            __syncthreads();   // win[] ready

            float rv[ZPL];

            // Prologue: stage slab 0 into buffer 0
            {
                const int wx0 = win[0][0], wy0 = win[0][1];
                const int gx = wx0 + tx, gy = wy0 + ty;
                const bool lat = ((unsigned)gx < RES) && ((unsigned)gy < RES);
                unsigned gaddr = (unsigned)((gy * RES) + gx);
                #pragma unroll
                for (int z = 0; z < ZPL; ++z) {
                    rv[z] = (lat && z < RES) ? vol[gaddr] : 0.0f;
                    gaddr += RES * RES;
                }
                #pragma unroll
                for (int z = 0; z < ZPL; ++z) slab[0][z][ty][tx] = rv[z];
            }
            __syncthreads();   // slab 0 ready

            int sc = 0;
            for (int k = 0; k < NSLAB; ++k) {
                const int cur = k & 1;
                const int wx0 = win[k][0];
                const int wy0 = win[k][1];
                const int zk  = k * ZSL;

                // Issue next slab's loads EARLY (hide under consume)
                if (k + 1 < NSLAB) {
                    const int nzk = zk + ZSL;
                    const int nwx0 = win[k + 1][0], nwy0 = win[k + 1][1];
                    const int gx = nwx0 + tx, gy = nwy0 + ty;
                    const bool lat = ((unsigned)gx < RES) && ((unsigned)gy < RES);
                    unsigned gaddr = (unsigned)(((nzk) * RES + gy) * RES + gx);
                    #pragma unroll
                    for (int z = 0; z < ZPL; ++z) {
                        rv[z] = (lat && (nzk + z) < RES) ? vol[gaddr] : 0.0f;
                        gaddr += RES * RES;
                    }
                }

                const float zend = (k == NSLAB - 1) ? 1e30f : (float)(zk + ZSL);

                // Closed-form sample count for this slab (off-by-one safe:
                // misassigned samples fail the window check -> cornerf).
                int sc_end;
                if (qz > 1e-9f) {
                    sc_end = (int)ceilf((zend - basez) / qz);
                    if (sc_end < sc) sc_end = sc;
                    if (sc_end > NS) sc_end = NS;
                } else {
                    sc_end = (fmaf(qz, (float)sc, basez) < zend) ? NS : sc;
                }

                const float* sb = &slab[cur][0][0][0];

                #pragma unroll 2
                for (int s = sc; s < sc_end; ++s) {
                    const float fs = (float)s;
                    const float cz = fmaf(qz, fs, basez);
                    const float cx = fmaf(qx, fs, basex);
                    const float cy = fmaf(qy, fs, basey);
                    const float x0f = floorf(cx), y0f = floorf(cy), z0f = floorf(cz);
                    const float fx = cx - x0f, fy = cy - y0f, fz = cz - z0f;
                    const int ix0 = (int)x0f, iy0 = (int)y0f, iz0 = (int)z0f;

                    const bool hit =
                        (unsigned)(ix0 - wx0) <= (unsigned)(WXS - 2) &&
                        (unsigned)(iy0 - wy0) <= (unsigned)(WYS - 2) &&
                        (unsigned)(iz0 - zk)  <= (unsigned)(ZSL - 1) &&
                        x0f == x0f;

                    // Branchless LDS lerp with clamped indices (always safe)
                    const int lx = clampi(ix0 - wx0, 0, WXS - 2);
                    const int ly = clampi(iy0 - wy0, 0, WYS - 2);
                    const int lz = clampi(iz0 - zk,  0, ZSL - 1);
                    const float* p = sb + (lz * (WYS * WROW) + ly * WROW + lx);
                    const float2 A0 = load_f2(p);
                    const float2 A1 = load_f2(p + WROW);
                    const float2 B0 = load_f2(p + WYS * WROW);
                    const float2 B1 = load_f2(p + WYS * WROW + WROW);
                    const float x00 = fmaf(fx, A0.y - A0.x, A0.x);
                    const float x10 = fmaf(fx, A1.y - A1.x, A1.x);
                    const float x01 = fmaf(fx, B0.y - B0.x, B0.x);
                    const float x11 = fmaf(fx, B1.y - B1.x, B1.x);
                    const float y0v = fmaf(fy, x10 - x00, x00);
                    const float y1v = fmaf(fy, x11 - x01, x01);
                    const float lv  = fmaf(fz, y1v - y0v, y0v);

                    if (hit) {
                        sum += lv;
                    } else {
                        const float gxw = 1.0f - fx, gyw = 1.0f - fy, gzw = 1.0f - fz;
                        sum += cornerf(vol, x0f,       y0f,       z0f,       gxw * gyw * gzw);
                        sum += cornerf(vol, x0f + 1.f, y0f,       z0f,       fx  * gyw * gzw);
                        sum += cornerf(vol, x0f,       y0f + 1.f, z0f,       gxw * fy  * gzw);
                        sum += cornerf(vol, x0f + 1.f, y0f + 1.f, z0f,       fx  * fy  * gzw);
                        sum += cornerf(vol, x0f,       y0f,       z0f + 1.f, gxw * gyw * fz);
                        sum += cornerf(vol, x0f + 1.f, y0f,       z0f + 1.f, fx  * gyw * fz);
                        sum += cornerf(vol, x0f,       y0f + 1.f, z0f + 1.f, gxw * fy  * fz);
                        sum += cornerf(vol, x0f + 1.f, y0f + 1.f, z0f + 1.f, fx  * fy  * fz);
                    }
                }
                sc = sc_end;

                // Write next slab to the other buffer; single barrier/slab.
                if (k + 1 < NSLAB) {
                    #pragma unroll
                    for (int z = 0; z < ZPL; ++z) slab[cur ^ 1][z][ty][tx] = rv[z];
                    __syncthreads();   // slab k+1 ready
                }
            }
        } else {
            // Direct-gather path (mode 0 / degenerate corner rays)
            #pragma unroll 4
            for (int s = 0; s < NS; ++s) {
                const float fs = (float)s;
                const float cx = fmaf(qx, fs, basex);
                const float cy = fmaf(qy, fs, basey);
                const float cz = fmaf(qz, fs, basez);
                const float x0 = floorf(cx), y0 = floorf(cy), z0 = floorf(cz);
                const float fx = cx - x0, fy = cy - y0, fz = cz - z0;
                const float gx = 1.0f - fx, gy = 1.0f - fy, gz = 1.0f - fz;

                if (x0 >= 0.f && x0 <= 126.f &&
                    y0 >= 0.f && y0 <= 126.f &&
                    z0 >= 0.f && z0 <= 126.f) {
                    const int base = (((int)z0) * RES + ((int)y0)) * RES + ((int)x0);
                    const float2 vA = load_f2(vol + base);
                    const float2 vB = load_f2(vol + base + RES);
                    const float2 vC = load_f2(vol + base + RES * RES);
                    const float2 vD = load_f2(vol + base + RES * RES + RES);
                    const float gygz = gy * gz, fygz = fy * gz;
                    const float gyfz = gy * fz, fyfz = fy * fz;
                    sum += (vA.x * gx + vA.y * fx) * gygz
                         + (vB.x * gx + vB.y * fx) * fygz
                         + (vC.x * gx + vC.y * fx) * gyfz
                         + (vD.x * gx + vD.y * fx) * fyfz;
                } else {
                    sum += cornerf(vol, x0,       y0,       z0,       gx * gy * gz);
                    sum += cornerf(vol, x0 + 1.f, y0,       z0,       fx * gy * gz);
                    sum += cornerf(vol, x0,       y0 + 1.f, z0,       gx * fy * gz);
                    sum += cornerf(vol, x0 + 1.f, y0 + 1.f, z0,       fx * fy * gz);
                    sum += cornerf(vol, x0,       y0,       z0 + 1.f, gx * gy * fz);
                    sum += cornerf(vol, x0 + 1.f, y0,       z0 + 1.f, fx * gy * fz);
                    sum += cornerf(vol, x0,       y0 + 1.f, z0 + 1.f, gx * fy * fz);
                    sum += cornerf(vol, x0 + 1.f, y0 + 1.f, z0 + 1.f, fx * fy * fz);
                }
            }
        }

        if (inImg) {
            const float delta = range * (1.0f / 64.0f);
            out[i * W + j] = valid ? sum * delta : 0.0f;
        }
    }
}

extern "C" void kernel_launch(void* const* d_in, const int* in_sizes, int n_in,
                              void* d_out, int out_size, void* d_ws, size_t ws_size,
                              hipStream_t stream) {
    const float* vol  = (const float*)d_in[0];
    const float* wvt  = (const float*)d_in[1];
    const float* proj = (const float*)d_in[2];
    const float* cam  = (const float*)d_in[3];
    const float* bbox = (const float*)d_in[4];
    const int*   pH   = (const int*)d_in[5];
    const int*   pW   = (const int*)d_in[6];
    const int*   pmode= (const int*)d_in[7];
    float* out = (float*)d_out;

    int blocks = (out_size + 255) / 256;
    if (blocks < 1) blocks = 1;
    dsv_render<<<blocks, 256, 0, stream>>>(vol, wvt, proj, cam, bbox, pH, pW, pmode, out);
}